// Round 1
// baseline (396.748 us; speedup 1.0000x reference)
//
#include <hip/hip_runtime.h>
#include <cstdint>
#include <cstddef>

// Problem constants
#define NB 64
#define NR 36
#define NW 32
#define ND 1024

// workspace layout (in floats)
#define OFF_DOT   0ull
#define N_DOT     (4096ull * 2304ull)          // [s;x](4096) x im^T(2304)
#define OFF_G     (OFF_DOT + N_DOT)            // 64 x 36 x 36
#define N_G       (64ull * 36ull * 36ull)
#define OFF_W1    (OFF_G + N_G)                // 64*32  ||s||
#define OFF_XN    (OFF_W1 + 2048ull)           // 64*32  ||x||
#define OFF_IMN   (OFF_XN + 2048ull)           // 64*36  ||im||
#define OFF_S     (OFF_IMN + 2304ull)          // 64*64 scores
#define OFF_SOT   (OFF_S + 4096ull)            // 64*64 ot scores

// ---------------- K1: vector norms (s, x, im) ----------------
__global__ __launch_bounds__(256) void k_norms(const float* __restrict__ s,
                                               const float* __restrict__ x,
                                               const float* __restrict__ im,
                                               float* __restrict__ ws) {
  int b = blockIdx.x, y = blockIdx.y, tid = threadIdx.x;
  const float* v;
  float* outp;
  if (y < 32)      { v = s  + ((size_t)b*32 + y) * ND;        outp = ws + OFF_W1  + b*32 + y; }
  else if (y < 64) { v = x  + ((size_t)b*32 + (y-32)) * ND;   outp = ws + OFF_XN  + b*32 + (y-32); }
  else             { v = im + ((size_t)b*36 + (y-64)) * ND;   outp = ws + OFF_IMN + b*36 + (y-64); }
  float4 f = ((const float4*)v)[tid];                 // 256 threads * 4 = 1024
  float p = f.x*f.x + f.y*f.y + f.z*f.z + f.w*f.w;
  #pragma unroll
  for (int o = 32; o > 0; o >>= 1) p += __shfl_down(p, o, 64);
  __shared__ float red[4];
  if ((tid & 63) == 0) red[tid >> 6] = p;
  __syncthreads();
  if (tid == 0) *outp = sqrtf(red[0] + red[1] + red[2] + red[3]);
}

// ---------------- K2: per-image Gram G[i] = im_i @ im_i^T ----------------
__global__ __launch_bounds__(256) void k_gram(const float* __restrict__ im,
                                              float* __restrict__ ws) {
  int b = blockIdx.x, r = blockIdx.y, tid = threadIdx.x;
  float* G = ws + OFF_G + ((size_t)b*36 + r)*36;
  float4 my = ((const float4*)(im + ((size_t)b*36 + r)*ND))[tid];
  __shared__ float red[4];
  for (int rp = 0; rp < 36; ++rp) {
    float4 u = ((const float4*)(im + ((size_t)b*36 + rp)*ND))[tid];
    float p = my.x*u.x + my.y*u.y + my.z*u.z + my.w*u.w;
    #pragma unroll
    for (int o = 32; o > 0; o >>= 1) p += __shfl_down(p, o, 64);
    if ((tid & 63) == 0) red[tid >> 6] = p;
    __syncthreads();
    if (tid == 0) G[rp] = red[0] + red[1] + red[2] + red[3];
    __syncthreads();
  }
}

// ---------------- K3: fp32 GEMM  [s;x](4096x1024) @ im^T -> ws_dot (4096x2304) ----------------
// 128x64 tile, 8x8 microtile, TK=16
__global__ __launch_bounds__(128) void k_gemm(const float* __restrict__ s,
                                              const float* __restrict__ x,
                                              const float* __restrict__ im,
                                              float* __restrict__ outp) {
  __shared__ float As[16][128];
  __shared__ float Bs[16][68];   // +4 pad (keeps 16B row alignment: 272B)
  int tid = threadIdx.x;
  int bn = blockIdx.x, bm = blockIdx.y;
  const float* Ap = (bm < 16) ? s : x;
  int arow0 = (bm < 16) ? bm*128 : bm*128 - 2048;
  int tm = tid & 15, tn = tid >> 4;
  int m0 = tm*8, n0 = tn*8;
  float acc[8][8];
  #pragma unroll
  for (int i2 = 0; i2 < 8; ++i2)
    #pragma unroll
    for (int j = 0; j < 8; ++j) acc[i2][j] = 0.f;

  for (int kt = 0; kt < 1024; kt += 16) {
    __syncthreads();
    #pragma unroll
    for (int rep = 0; rep < 4; ++rep) {          // A tile: 128 rows x 16 k
      int idx = tid + 128*rep;
      int row = idx >> 2;
      int kq  = (idx & 3) << 2;
      float4 v = *(const float4*)(Ap + (size_t)(arow0 + row)*1024 + kt + kq);
      As[kq+0][row] = v.x; As[kq+1][row] = v.y; As[kq+2][row] = v.z; As[kq+3][row] = v.w;
    }
    #pragma unroll
    for (int rep = 0; rep < 2; ++rep) {          // B tile: 64 rows x 16 k
      int idx = tid + 128*rep;
      int row = idx >> 2;
      int kq  = (idx & 3) << 2;
      float4 v = *(const float4*)(im + (size_t)(bn*64 + row)*1024 + kt + kq);
      Bs[kq+0][row] = v.x; Bs[kq+1][row] = v.y; Bs[kq+2][row] = v.z; Bs[kq+3][row] = v.w;
    }
    __syncthreads();
    #pragma unroll
    for (int k = 0; k < 16; ++k) {
      float a[8], b[8];
      *(float4*)&a[0] = *(const float4*)&As[k][m0];
      *(float4*)&a[4] = *(const float4*)&As[k][m0+4];
      *(float4*)&b[0] = *(const float4*)&Bs[k][n0];
      *(float4*)&b[4] = *(const float4*)&Bs[k][n0+4];
      #pragma unroll
      for (int i2 = 0; i2 < 8; ++i2)
        #pragma unroll
        for (int j = 0; j < 8; ++j) acc[i2][j] = fmaf(a[i2], b[j], acc[i2][j]);
    }
  }
  #pragma unroll
  for (int i2 = 0; i2 < 8; ++i2) {
    size_t ro = (size_t)(bm*128 + m0 + i2)*2304 + bn*64 + n0;
    float4 v0 = make_float4(acc[i2][0], acc[i2][1], acc[i2][2], acc[i2][3]);
    float4 v1 = make_float4(acc[i2][4], acc[i2][5], acc[i2][6], acc[i2][7]);
    *(float4*)(outp + ro)     = v0;
    *(float4*)(outp + ro + 4) = v1;
  }
}

// ---------------- K4: per-pair scores + IPOT, one pair per wave ----------------
// lane l: h = l>>5 (r-half), w = l&31 (word). 18 r's per lane in registers.
template<int C>
__device__ __forceinline__ float dpp_add(float v) {
  return v + __int_as_float(__builtin_amdgcn_mov_dpp(__float_as_int(v), C, 0xF, 0xF, true));
}
template<int C>
__device__ __forceinline__ float dpp_max(float v) {
  return fmaxf(v, __int_as_float(__builtin_amdgcn_mov_dpp(__float_as_int(v), C, 0xF, 0xF, true)));
}
// sum over the 32 lanes of each half (bits 0..4), result in all lanes
__device__ __forceinline__ float bsum32(float v) {
  v = dpp_add<0xB1>(v);    // xor1 (quad_perm 1,0,3,2)
  v = dpp_add<0x4E>(v);    // xor2 (quad_perm 2,3,0,1)
  v = dpp_add<0x141>(v);   // xor7 (row_half_mirror)
  v = dpp_add<0x128>(v);   // xor8 (row_ror:8)
  v += __shfl_xor(v, 16, 64);
  return v;
}
__device__ __forceinline__ float bmax32(float v) {
  v = dpp_max<0xB1>(v);
  v = dpp_max<0x4E>(v);
  v = dpp_max<0x141>(v);
  v = dpp_max<0x128>(v);
  v = fmaxf(v, __shfl_xor(v, 16, 64));
  return v;
}

__global__ __launch_bounds__(256) void k_pair(const float* __restrict__ dotm,
                                              const float* __restrict__ Gm,
                                              const float* __restrict__ w1m,
                                              const float* __restrict__ xnm,
                                              const float* __restrict__ imnm,
                                              float* __restrict__ S,
                                              float* __restrict__ Sot) {
  int wid  = threadIdx.x >> 6;
  int pair = blockIdx.x * 4 + wid;           // 0..4095
  int c = pair >> 6, i = pair & 63;
  int l = threadIdx.x & 63;
  int h = l >> 5, w = l & 31;

  const float* drow = dotm + (size_t)(c*32 + w)*2304 + i*36 + h*18;
  const float* xrow = dotm + (size_t)(2048 + c*32 + w)*2304 + i*36 + h*18;
  float w1  = w1m[c*32 + w];
  float xnw = xnm[c*32 + w] + 1e-12f;

  float d0[18], Cm[18];
  #pragma unroll
  for (int m = 0; m < 18; ++m) d0[m] = drow[m];
  #pragma unroll
  for (int m = 0; m < 18; ++m) {
    float xv  = xrow[m];
    float inm = imnm[i*36 + h*18 + m] + 1e-12f;
    Cm[m] = 1.f - xv / (xnw * inm);          // OT cost matrix entry
  }

  // ---- attention chain: leaky -> l2norm over w -> softmax over r ----
  float f[18];
  #pragma unroll
  for (int m = 0; m < 18; ++m) f[m] = d0[m] > 0.f ? d0[m] : 0.1f * d0[m];
  #pragma unroll
  for (int m = 0; m < 18; ++m) {
    float t = bsum32(f[m] * f[m]);           // sum over w per r
    f[m] = f[m] / (sqrtf(t) + 1e-8f);
  }
  float p[18];
  float mx = -1e30f;
  #pragma unroll
  for (int m = 0; m < 18; ++m) { p[m] = 9.f * f[m]; mx = fmaxf(mx, p[m]); }
  mx = fmaxf(mx, __shfl_xor(mx, 32, 64));
  float sum = 0.f;
  #pragma unroll
  for (int m = 0; m < 18; ++m) { p[m] = __expf(p[m] - mx); sum += p[m]; }
  sum += __shfl_xor(sum, 32, 64);
  float inv = 1.f / sum;
  float num = 0.f;
  float a[18];
  #pragma unroll
  for (int m = 0; m < 18; ++m) { a[m] = p[m] * inv; num += a[m] * d0[m]; }
  num += __shfl_xor(num, 32, 64);

  // ---- w2^2 = a^T G a (G rows are wave-uniform -> scalar loads) ----
  float afull[36];
  #pragma unroll
  for (int m = 0; m < 18; ++m) {
    float o = __shfl_xor(a[m], 32, 64);
    afull[m]      = h ? o    : a[m];
    afull[18 + m] = h ? a[m] : o;
  }
  int iu = __builtin_amdgcn_readfirstlane(i);
  const float* Gi = Gm + (size_t)iu * 1296;
  float w2sq = 0.f;
  #pragma unroll
  for (int rp = 0; rp < 36; ++rp) {
    float inner = 0.f;
    #pragma unroll
    for (int rr = 0; rr < 36; ++rr) inner = fmaf(Gi[rp*36 + rr], afull[rr], inner);
    w2sq = fmaf(afull[rp], inner, w2sq);
  }
  float w2 = sqrtf(w2sq);
  float rs6 = 6.f * num / fmaxf(w1 * w2, 1e-8f);

  // ---- LSE over w ----
  float mw = bmax32(rs6);
  float se = bsum32(__expf(rs6 - mw));
  float sim = (mw + __logf(se)) * (1.f / 6.f);
  if (l == 0) S[i*64 + c] = sim;

  // ---- IPOT: 20 iterations, all in registers ----
  float Am[18], Qm[18], sg[18];
  #pragma unroll
  for (int m = 0; m < 18; ++m) {
    Am[m] = __expf(-2.f * Cm[m]);
    Qm[m] = Am[m];                            // Q_1 = A * T_0 (T_0 = 1)
    sg[m] = 1.f / 36.f;                       // sigma_0
  }
  float delta = 0.f;
  for (int it = 0; it < 20; ++it) {
    float t = 0.f;
    #pragma unroll
    for (int m = 0; m < 18; ++m) t = fmaf(Qm[m], sg[m], t);
    t += __shfl_xor(t, 32, 64);               // sum over all 36 r
    delta = __builtin_amdgcn_rcpf(32.f * t);  // delta = 1/(W * (Q sigma))
    #pragma unroll
    for (int m = 0; m < 18; ++m) {
      float q = bsum32(Qm[m] * delta);        // sum over w
      sg[m] = __builtin_amdgcn_rcpf(36.f * q);// sigma = 1/(R * (Q^T delta))
    }
    if (it < 19) {
      #pragma unroll
      for (int m = 0; m < 18; ++m) Qm[m] = delta * Am[m] * Qm[m] * sg[m]; // Q_{k+1}
    }
  }
  float ot = 0.f;
  #pragma unroll
  for (int m = 0; m < 18; ++m) ot = fmaf(Cm[m], delta * Qm[m] * sg[m], ot); // C . T_20
  ot += __shfl_xor(ot, 32, 64);
  ot = bsum32(ot);
  if (l == 0) Sot[i*64 + c] = -ot;
}

// ---------------- K5: final contrastive reduction ----------------
__global__ __launch_bounds__(256) void k_reduce(const float* __restrict__ Sg,
                                                const float* __restrict__ Sotg,
                                                float* __restrict__ outp) {
  __shared__ float s[4096];
  __shared__ float so[4096];
  __shared__ float red0[256], red1[256];
  int tid = threadIdx.x;
  for (int e = tid; e < 4096; e += 256) { s[e] = Sg[e]; so[e] = Sotg[e]; }
  __syncthreads();
  float m0 = 0.f, m1 = 0.f;
  if (tid < 64) {                      // row max (cost_s): i = tid
    int i = tid;
    float di = s[i*65], dio = so[i*65];
    for (int c2 = 0; c2 < 64; ++c2) {
      if (c2 == i) continue;
      float cs  = fmaxf(0.2f + s[i*64 + c2]  - di,  0.f);
      float cso = fmaxf(0.2f + so[i*64 + c2] - dio, 0.f);
      m0 = fmaxf(m0, cs + 0.1f * cso);
      m1 = fmaxf(m1, cso);
    }
  } else if (tid < 128) {              // col max (cost_im): c = tid-64
    int c2 = tid - 64;
    float dc = s[c2*65], dco = so[c2*65];
    for (int i = 0; i < 64; ++i) {
      if (i == c2) continue;
      float cim  = fmaxf(0.2f + s[i*64 + c2]  - dc,  0.f);
      float cimo = fmaxf(0.2f + so[i*64 + c2] - dco, 0.f);
      m0 = fmaxf(m0, cim + 0.1f * cimo);
      m1 = fmaxf(m1, cimo);
    }
  }
  red0[tid] = m0; red1[tid] = m1;
  __syncthreads();
  if (tid == 0) {
    float a0 = 0.f, a1 = 0.f;
    for (int t = 0; t < 128; ++t) { a0 += red0[t]; a1 += red1[t]; }
    outp[0] = a0;   // sum(cost_s)+sum(cost_im)   (combined with alpha*ot)
    outp[1] = a1;   // sum(cost_s_ot)+sum(cost_im_ot)
  }
}

extern "C" void kernel_launch(void* const* d_in, const int* in_sizes, int n_in,
                              void* d_out, int out_size, void* d_ws, size_t ws_size,
                              hipStream_t stream) {
  (void)in_sizes; (void)n_in; (void)out_size; (void)ws_size;
  const float* im = (const float*)d_in[0];
  const float* s  = (const float*)d_in[1];
  // d_in[2] = s_l (uniform == W, unused)
  const float* x  = (const float*)d_in[3];
  float* ws  = (float*)d_ws;
  float* out = (float*)d_out;

  k_norms<<<dim3(64, 100), 256, 0, stream>>>(s, x, im, ws);
  k_gram <<<dim3(64, 36),  256, 0, stream>>>(im, ws);
  k_gemm <<<dim3(36, 32),  128, 0, stream>>>(s, x, im, ws + OFF_DOT);
  k_pair <<<dim3(1024),    256, 0, stream>>>(ws + OFF_DOT, ws + OFF_G, ws + OFF_W1,
                                             ws + OFF_XN, ws + OFF_IMN,
                                             ws + OFF_S, ws + OFF_SOT);
  k_reduce<<<dim3(1),      256, 0, stream>>>(ws + OFF_S, ws + OFF_SOT, out);
}

// Round 2
// 128.072 us; speedup vs baseline: 3.0979x; 3.0979x over previous
//
#include <hip/hip_runtime.h>
#include <cstdint>
#include <cstddef>

// Problem constants: B=64, R=36, W=32, D=1024
// A = [s;x] : 4096 x 1024 (rows 0..2047 = s words, 2048..4095 = x words)
// B = im    : 2304 x 1024 (row-major = B^T input form for dot[m][n] = A[m]·B[n])
// dot       : 4096 x 2304 (bf16)

typedef __attribute__((ext_vector_type(8))) short short8;
typedef __attribute__((ext_vector_type(4))) float f32x4;

__device__ __forceinline__ unsigned short f2bf(float f) {
  unsigned u = __float_as_uint(f);
  u += 0x7FFFu + ((u >> 16) & 1u);
  return (unsigned short)(u >> 16);
}
__device__ __forceinline__ float bf2f(unsigned short h) {
  return __uint_as_float(((unsigned)h) << 16);
}

// ---------------- K1: convert fp32 -> bf16 rows + row L2 norms ----------------
__global__ __launch_bounds__(256) void k_prep(const float* __restrict__ s,
                                              const float* __restrict__ x,
                                              const float* __restrict__ im,
                                              unsigned short* __restrict__ Ab,
                                              unsigned short* __restrict__ Bb,
                                              float* __restrict__ w1,
                                              float* __restrict__ xn,
                                              float* __restrict__ imn) {
  int row = blockIdx.x, tid = threadIdx.x;
  const float* src; unsigned short* dst; float* np;
  if (row < 2048)      { src = s  + (size_t)row * 1024;         dst = Ab + (size_t)row * 1024;         np = w1  + row; }
  else if (row < 4096) { src = x  + (size_t)(row - 2048) * 1024; dst = Ab + (size_t)row * 1024;         np = xn  + (row - 2048); }
  else                 { src = im + (size_t)(row - 4096) * 1024; dst = Bb + (size_t)(row - 4096) * 1024; np = imn + (row - 4096); }
  float4 f = ((const float4*)src)[tid];
  ushort4 h;
  h.x = f2bf(f.x); h.y = f2bf(f.y); h.z = f2bf(f.z); h.w = f2bf(f.w);
  ((ushort4*)dst)[tid] = h;
  float p = f.x*f.x + f.y*f.y + f.z*f.z + f.w*f.w;
  #pragma unroll
  for (int o = 32; o > 0; o >>= 1) p += __shfl_down(p, o, 64);
  __shared__ float red[4];
  if ((tid & 63) == 0) red[tid >> 6] = p;
  __syncthreads();
  if (tid == 0) *np = sqrtf(red[0] + red[1] + red[2] + red[3]);
}

// ---------------- K2: per-image Gram G[i] = im_i @ im_i^T (fp32, wave-parallel) ----------------
__global__ __launch_bounds__(256) void k_gram(const float* __restrict__ im,
                                              float* __restrict__ G) {
  int b = blockIdx.x, r = blockIdx.y;
  int wid = threadIdx.x >> 6, l = threadIdx.x & 63;
  const float* rowr = im + ((size_t)b*36 + r) * 1024;
  float4 my[4];
  #pragma unroll
  for (int j = 0; j < 4; ++j) my[j] = ((const float4*)rowr)[j*64 + l];
  float* Gr = G + ((size_t)b*36 + r) * 36;
  for (int rp = wid; rp < 36; rp += 4) {
    const float* rowp = im + ((size_t)b*36 + rp) * 1024;
    float p = 0.f;
    #pragma unroll
    for (int j = 0; j < 4; ++j) {
      float4 u = ((const float4*)rowp)[j*64 + l];
      p += my[j].x*u.x + my[j].y*u.y + my[j].z*u.z + my[j].w*u.w;
    }
    #pragma unroll
    for (int o = 32; o > 0; o >>= 1) p += __shfl_down(p, o, 64);
    if (l == 0) Gr[rp] = p;
  }
}

// ---------------- K3: bf16 MFMA GEMM (m97 structure): dot = A @ B^T ----------------
// 128x128 tile, 4 waves (2x2 of 64x64), BK=32, global_load_lds width 16
__global__ __launch_bounds__(256) void k_gemm_mfma(const unsigned short* __restrict__ A,
                                                   const unsigned short* __restrict__ B,
                                                   unsigned short* __restrict__ dot) {
  __shared__ unsigned short lA[128 * 32];
  __shared__ unsigned short lB[128 * 32];
  int tid = threadIdx.x;
  int bn = blockIdx.x * 128, bm = blockIdx.y * 128;
  int wid = tid >> 6, l = tid & 63;
  int wr = (wid >> 1) * 64, wc = (wid & 1) * 64;
  int lr = l & 15, lq = l >> 4;

  f32x4 acc[4][4] = {};

  // staging: thread t loads 16B = 8 bf16; idx = t (+256): row = idx>>2, k-quad = (idx&3)*8
  // LDS byte offset = idx*16 == linear [row][k] layout -> matches global_load_lds lane order
  int row_a = tid >> 2;
  int kq = (tid & 3) * 8;
  const unsigned short* gA = A + (size_t)(bm + row_a) * 1024 + kq;
  const unsigned short* gB = B + (size_t)(bn + row_a) * 1024 + kq;
  unsigned loff = (unsigned)tid * 16u;

  for (int kt = 0; kt < 1024; kt += 32) {
    __builtin_amdgcn_global_load_lds(
        (const __attribute__((address_space(1))) void*)(gA + kt),
        (__attribute__((address_space(3))) void*)((char*)lA + loff), 16, 0, 0);
    __builtin_amdgcn_global_load_lds(
        (const __attribute__((address_space(1))) void*)(gA + 64*1024 + kt),
        (__attribute__((address_space(3))) void*)((char*)lA + 4096 + loff), 16, 0, 0);
    __builtin_amdgcn_global_load_lds(
        (const __attribute__((address_space(1))) void*)(gB + kt),
        (__attribute__((address_space(3))) void*)((char*)lB + loff), 16, 0, 0);
    __builtin_amdgcn_global_load_lds(
        (const __attribute__((address_space(1))) void*)(gB + 64*1024 + kt),
        (__attribute__((address_space(3))) void*)((char*)lB + 4096 + loff), 16, 0, 0);
    __syncthreads();   // compiler emits vmcnt(0) drain before barrier

    short8 af[4], bfr[4];
    #pragma unroll
    for (int mi = 0; mi < 4; ++mi)
      af[mi] = *(const short8*)&lA[(wr + mi*16 + lr) * 32 + lq * 8];
    #pragma unroll
    for (int ni = 0; ni < 4; ++ni)
      bfr[ni] = *(const short8*)&lB[(wc + ni*16 + lr) * 32 + lq * 8];
    #pragma unroll
    for (int mi = 0; mi < 4; ++mi)
      #pragma unroll
      for (int ni = 0; ni < 4; ++ni)
        acc[mi][ni] = __builtin_amdgcn_mfma_f32_16x16x32_bf16(af[mi], bfr[ni], acc[mi][ni], 0, 0, 0);
    __syncthreads();   // protect LDS before next stage
  }

  // C/D layout (m89-verified): col = lane&15, row = (lane>>4)*4 + reg
  #pragma unroll
  for (int mi = 0; mi < 4; ++mi)
    #pragma unroll
    for (int ni = 0; ni < 4; ++ni) {
      int gcol = bn + wc + ni*16 + lr;
      #pragma unroll
      for (int q = 0; q < 4; ++q) {
        int grow = bm + wr + mi*16 + lq*4 + q;
        dot[(size_t)grow * 2304 + gcol] = f2bf(acc[mi][ni][q]);
      }
    }
}

// ---------------- K4: per-pair scores + IPOT, one pair per wave ----------------
template<int C>
__device__ __forceinline__ float dpp_add(float v) {
  return v + __int_as_float(__builtin_amdgcn_mov_dpp(__float_as_int(v), C, 0xF, 0xF, true));
}
template<int C>
__device__ __forceinline__ float dpp_max(float v) {
  return fmaxf(v, __int_as_float(__builtin_amdgcn_mov_dpp(__float_as_int(v), C, 0xF, 0xF, true)));
}
__device__ __forceinline__ float bsum32(float v) {
  v = dpp_add<0xB1>(v);    // xor1
  v = dpp_add<0x4E>(v);    // xor2
  v = dpp_add<0x141>(v);   // xor7 (half mirror)
  v = dpp_add<0x128>(v);   // xor8 (row_ror:8)
  v += __shfl_xor(v, 16, 64);
  return v;
}
__device__ __forceinline__ float bmax32(float v) {
  v = dpp_max<0xB1>(v);
  v = dpp_max<0x4E>(v);
  v = dpp_max<0x141>(v);
  v = dpp_max<0x128>(v);
  v = fmaxf(v, __shfl_xor(v, 16, 64));
  return v;
}

__global__ __launch_bounds__(256) void k_pair(const unsigned short* __restrict__ dotb,
                                              const float* __restrict__ Gm,
                                              const float* __restrict__ w1m,
                                              const float* __restrict__ xnm,
                                              const float* __restrict__ imnm,
                                              float* __restrict__ S,
                                              float* __restrict__ Sot) {
  int wid  = threadIdx.x >> 6;
  int pair = blockIdx.x * 4 + wid;           // 0..4095
  int c = pair >> 6, i = pair & 63;
  int l = threadIdx.x & 63;
  int h = l >> 5, w = l & 31;

  const unsigned short* drow = dotb + (size_t)(c*32 + w) * 2304 + i*36 + h*18;
  const unsigned short* xrow = drow + (size_t)2048 * 2304;
  float w1  = w1m[c*32 + w];
  float xnw = xnm[c*32 + w] + 1e-12f;

  float d0[18], Cm[18];
  #pragma unroll
  for (int m = 0; m < 18; ++m) d0[m] = bf2f(drow[m]);
  #pragma unroll
  for (int m = 0; m < 18; ++m) {
    float xv  = bf2f(xrow[m]);
    float inm = imnm[i*36 + h*18 + m] + 1e-12f;
    Cm[m] = 1.f - xv / (xnw * inm);
  }

  // ---- attention: leaky -> l2norm over w -> softmax over r ----
  float f[18];
  #pragma unroll
  for (int m = 0; m < 18; ++m) f[m] = d0[m] > 0.f ? d0[m] : 0.1f * d0[m];
  #pragma unroll
  for (int m = 0; m < 18; ++m) {
    float t = bsum32(f[m] * f[m]);
    f[m] = f[m] / (sqrtf(t) + 1e-8f);
  }
  float p[18];
  float mx = -1e30f;
  #pragma unroll
  for (int m = 0; m < 18; ++m) { p[m] = 9.f * f[m]; mx = fmaxf(mx, p[m]); }
  mx = fmaxf(mx, __shfl_xor(mx, 32, 64));
  float sum = 0.f;
  #pragma unroll
  for (int m = 0; m < 18; ++m) { p[m] = __expf(p[m] - mx); sum += p[m]; }
  sum += __shfl_xor(sum, 32, 64);
  float inv = 1.f / sum;
  float num = 0.f;
  float a[18];
  #pragma unroll
  for (int m = 0; m < 18; ++m) { a[m] = p[m] * inv; num += a[m] * d0[m]; }
  num += __shfl_xor(num, 32, 64);

  // ---- w2^2 = a^T G a (G rows wave-uniform -> scalar loads) ----
  float afull[36];
  #pragma unroll
  for (int m = 0; m < 18; ++m) {
    float o = __shfl_xor(a[m], 32, 64);
    afull[m]      = h ? o    : a[m];
    afull[18 + m] = h ? a[m] : o;
  }
  int iu = __builtin_amdgcn_readfirstlane(i);
  const float* Gi = Gm + (size_t)iu * 1296;
  float w2sq = 0.f;
  #pragma unroll
  for (int rp = 0; rp < 36; ++rp) {
    float inner = 0.f;
    #pragma unroll
    for (int rr = 0; rr < 36; ++rr) inner = fmaf(Gi[rp*36 + rr], afull[rr], inner);
    w2sq = fmaf(afull[rp], inner, w2sq);
  }
  float w2 = sqrtf(w2sq);
  float rs6 = 6.f * num / fmaxf(w1 * w2, 1e-8f);

  // ---- LSE over w ----
  float mw = bmax32(rs6);
  float se = bsum32(__expf(rs6 - mw));
  float sim = (mw + __logf(se)) * (1.f / 6.f);
  if (l == 0) S[i*64 + c] = sim;

  // ---- IPOT: 20 iterations, all in registers ----
  float Am[18], Qm[18], sg[18];
  #pragma unroll
  for (int m = 0; m < 18; ++m) {
    Am[m] = __expf(-2.f * Cm[m]);
    Qm[m] = Am[m];
    sg[m] = 1.f / 36.f;
  }
  float delta = 0.f;
  for (int it = 0; it < 20; ++it) {
    float t = 0.f;
    #pragma unroll
    for (int m = 0; m < 18; ++m) t = fmaf(Qm[m], sg[m], t);
    t += __shfl_xor(t, 32, 64);
    delta = __builtin_amdgcn_rcpf(32.f * t);
    #pragma unroll
    for (int m = 0; m < 18; ++m) {
      float q = bsum32(Qm[m] * delta);
      sg[m] = __builtin_amdgcn_rcpf(36.f * q);
    }
    if (it < 19) {
      #pragma unroll
      for (int m = 0; m < 18; ++m) Qm[m] = delta * Am[m] * Qm[m] * sg[m];
    }
  }
  float ot = 0.f;
  #pragma unroll
  for (int m = 0; m < 18; ++m) ot = fmaf(Cm[m], delta * Qm[m] * sg[m], ot);
  ot += __shfl_xor(ot, 32, 64);
  ot = bsum32(ot);
  if (l == 0) Sot[i*64 + c] = -ot;
}

// ---------------- K5: final contrastive reduction ----------------
__global__ __launch_bounds__(256) void k_reduce(const float* __restrict__ Sg,
                                                const float* __restrict__ Sotg,
                                                float* __restrict__ outp) {
  __shared__ float s[4096];
  __shared__ float so[4096];
  __shared__ float red0[256], red1[256];
  int tid = threadIdx.x;
  for (int e = tid; e < 4096; e += 256) { s[e] = Sg[e]; so[e] = Sotg[e]; }
  __syncthreads();
  float m0 = 0.f, m1 = 0.f;
  if (tid < 64) {
    int i = tid;
    float di = s[i*65], dio = so[i*65];
    for (int c2 = 0; c2 < 64; ++c2) {
      if (c2 == i) continue;
      float cs  = fmaxf(0.2f + s[i*64 + c2]  - di,  0.f);
      float cso = fmaxf(0.2f + so[i*64 + c2] - dio, 0.f);
      m0 = fmaxf(m0, cs + 0.1f * cso);
      m1 = fmaxf(m1, cso);
    }
  } else if (tid < 128) {
    int c2 = tid - 64;
    float dc = s[c2*65], dco = so[c2*65];
    for (int i = 0; i < 64; ++i) {
      if (i == c2) continue;
      float cim  = fmaxf(0.2f + s[i*64 + c2]  - dc,  0.f);
      float cimo = fmaxf(0.2f + so[i*64 + c2] - dco, 0.f);
      m0 = fmaxf(m0, cim + 0.1f * cimo);
      m1 = fmaxf(m1, cimo);
    }
  }
  red0[tid] = m0; red1[tid] = m1;
  __syncthreads();
  if (tid == 0) {
    float a0 = 0.f, a1 = 0.f;
    for (int t = 0; t < 128; ++t) { a0 += red0[t]; a1 += red1[t]; }
    outp[0] = a0;
    outp[1] = a1;
  }
}

extern "C" void kernel_launch(void* const* d_in, const int* in_sizes, int n_in,
                              void* d_out, int out_size, void* d_ws, size_t ws_size,
                              hipStream_t stream) {
  (void)in_sizes; (void)n_in; (void)out_size; (void)ws_size;
  const float* im = (const float*)d_in[0];
  const float* s  = (const float*)d_in[1];
  // d_in[2] = s_l (uniform == W, unused)
  const float* x  = (const float*)d_in[3];
  float* out = (float*)d_out;

  // workspace layout (total ~32.4 MB, proven footprint was 38.1 MB)
  unsigned short* Ab   = (unsigned short*)d_ws;              // 4096*1024 bf16
  unsigned short* Bb   = Ab + (size_t)4096 * 1024;           // 2304*1024 bf16
  unsigned short* dotb = Bb + (size_t)2304 * 1024;           // 4096*2304 bf16
  float* G   = (float*)(dotb + (size_t)4096 * 2304);         // 64*36*36
  float* w1  = G + 64*36*36;
  float* xn  = w1 + 2048;
  float* imn = xn + 2048;
  float* S   = imn + 2304;
  float* Sot = S + 4096;

  k_prep<<<dim3(6400), 256, 0, stream>>>(s, x, im, Ab, Bb, w1, xn, imn);
  k_gram<<<dim3(64, 36), 256, 0, stream>>>(im, G);
  k_gemm_mfma<<<dim3(18, 32), 256, 0, stream>>>(Ab, Bb, dotb);
  k_pair<<<dim3(1024), 256, 0, stream>>>(dotb, G, w1, xn, imn, S, Sot);
  k_reduce<<<dim3(1), 256, 0, stream>>>(S, Sot, out);
}